// Round 1
// baseline (1923.885 us; speedup 1.0000x reference)
//
#include <hip/hip_runtime.h>

#define NSTEPS 20

// Tiny MLP: 4 -> 30 -> 5 -> 30 -> 5 -> 30 -> 2, returns output column COL.
// All weight reads are wave-uniform (constant offsets from kernel args) ->
// compiler emits s_load into SGPRs; FMAs take one SGPR operand each.
template<int COL>
__device__ __forceinline__ float evalnet(
    float f0, float f1, float f2, float f3,
    const float* __restrict__ W1, const float* __restrict__ b1,
    const float* __restrict__ W2, const float* __restrict__ b2,
    const float* __restrict__ W3, const float* __restrict__ b3,
    const float* __restrict__ W4, const float* __restrict__ b4,
    const float* __restrict__ W5, const float* __restrict__ b5,
    const float* __restrict__ W6, const float* __restrict__ b6)
{
    float h1[30];
#pragma unroll
    for (int j = 0; j < 30; ++j) {
        float a = b1[j];
        a = fmaf(f0, W1[0 * 30 + j], a);
        a = fmaf(f1, W1[1 * 30 + j], a);
        a = fmaf(f2, W1[2 * 30 + j], a);
        a = fmaf(f3, W1[3 * 30 + j], a);
        h1[j] = fmaxf(a, 0.0f);
    }
    float h2[5];
#pragma unroll
    for (int c = 0; c < 5; ++c) {
        float a = b2[c];
#pragma unroll
        for (int k = 0; k < 30; ++k) a = fmaf(h1[k], W2[k * 5 + c], a);
        h2[c] = a;
    }
    float h3[30];
#pragma unroll
    for (int j = 0; j < 30; ++j) {
        float a = b3[j];
#pragma unroll
        for (int k = 0; k < 5; ++k) a = fmaf(h2[k], W3[k * 30 + j], a);
        h3[j] = fmaxf(a, 0.0f);
    }
    float h4[5];
#pragma unroll
    for (int c = 0; c < 5; ++c) {
        float a = b4[c];
#pragma unroll
        for (int k = 0; k < 30; ++k) a = fmaf(h3[k], W4[k * 5 + c], a);
        h4[c] = a;
    }
    float h5[30];
#pragma unroll
    for (int j = 0; j < 30; ++j) {
        float a = b5[j];
#pragma unroll
        for (int k = 0; k < 5; ++k) a = fmaf(h4[k], W5[k * 30 + j], a);
        h5[j] = fmaxf(a, 0.0f);
    }
    float o = b6[COL];
#pragma unroll
    for (int k = 0; k < 30; ++k) o = fmaf(h5[k], W6[k * 2 + COL], o);
    return o;
}

__global__ __launch_bounds__(256) void mc_hedge_kernel(
    const float* __restrict__ S0, const float* __restrict__ Kv,
    const float* __restrict__ Tv, const float* __restrict__ BM,
    const float* __restrict__ W1, const float* __restrict__ b1,
    const float* __restrict__ W2, const float* __restrict__ b2,
    const float* __restrict__ W3, const float* __restrict__ b3,
    const float* __restrict__ W4, const float* __restrict__ b4,
    const float* __restrict__ W5, const float* __restrict__ b5,
    const float* __restrict__ W6, const float* __restrict__ b6,
    float* __restrict__ out, int Btot)
{
    const int i = blockIdx.x * blockDim.x + threadIdx.x;
    if (i >= Btot) return;

    float price = S0[i];
    const float Kk = Kv[i];
    const float T  = Tv[i];
    const float logK = __logf(Kk);
    float hedge = 0.0f;

    const float* bmrow = BM + (size_t)i * NSTEPS;

#pragma unroll 1
    for (int idx = 0; idx < NSTEPS; ++idx) {
        // exact division so time==0.5 / ==1.0 compare bit-exactly vs reference
        const float time = (float)(idx + 1) / (float)NSTEPS;
        const float do_comp = (time <= T) ? 1.0f : 0.0f;
        const float inc = bmrow[idx] * (1.0f / (float)NSTEPS);
        const float Tmt = T - time;

        // eval 1: leverage = net(feats(price_old))[0]
        float lp = __logf(price) - logK;
        const float lev = evalnet<0>(price, time, Tmt, lp,
                                     W1, b1, W2, b2, W3, b3, W4, b4, W5, b5, W6, b6);
        price = price + do_comp * lev * price * inc;

        // eval 2: hedge increment = net(feats(price_new))[1] * inc
        lp = __logf(price) - logK;
        const float hed = evalnet<1>(price, time, Tmt, lp,
                                     W1, b1, W2, b2, W3, b3, W4, b4, W5, b5, W6, b6) * inc;
        hedge = hedge + do_comp * hed;
    }

    const float payoff = fmaxf(price - Kk, 0.0f);
    out[i] = payoff - hedge;
}

extern "C" void kernel_launch(void* const* d_in, const int* in_sizes, int n_in,
                              void* d_out, int out_size, void* d_ws, size_t ws_size,
                              hipStream_t stream)
{
    const float* S0 = (const float*)d_in[0];
    const float* Kv = (const float*)d_in[1];
    const float* Tv = (const float*)d_in[2];
    const float* BM = (const float*)d_in[3];
    const float* W1 = (const float*)d_in[4];
    const float* b1 = (const float*)d_in[5];
    const float* W2 = (const float*)d_in[6];
    const float* b2 = (const float*)d_in[7];
    const float* W3 = (const float*)d_in[8];
    const float* b3 = (const float*)d_in[9];
    const float* W4 = (const float*)d_in[10];
    const float* b4 = (const float*)d_in[11];
    const float* W5 = (const float*)d_in[12];
    const float* b5 = (const float*)d_in[13];
    const float* W6 = (const float*)d_in[14];
    const float* b6 = (const float*)d_in[15];

    float* out = (float*)d_out;
    const int B = in_sizes[0];
    const int block = 256;
    const int grid = (B + block - 1) / block;

    mc_hedge_kernel<<<grid, block, 0, stream>>>(
        S0, Kv, Tv, BM,
        W1, b1, W2, b2, W3, b3, W4, b4, W5, b5, W6, b6,
        out, B);
}